// Round 1
// baseline (81.889 us; speedup 1.0000x reference)
//
#include <hip/hip_runtime.h>
#include <math.h>

// Problem constants (match reference)
#define B_  4
#define C_  128
#define H_  240
#define W_  320
#define N_  1024
#define NPTS (B_ * N_)          // 4096
#define HW_ (H_ * W_)

__device__ __forceinline__ float wave_reduce(float v) {
    // 64-lane butterfly sum
    #pragma unroll
    for (int off = 32; off > 0; off >>= 1)
        v += __shfl_xor(v, off, 64);
    return v;
}

// One block (128 threads = 128 channels) per point.
__global__ __launch_bounds__(128) void gn_point_kernel(
    const float* __restrict__ Fa, const float* __restrict__ Fb,
    const float* __restrict__ ma, const float* __restrict__ mb,
    const float* __restrict__ noise,
    float* __restrict__ ws_e1, float* __restrict__ ws_ld)
{
    const int p = blockIdx.x;            // 0..4095
    const int b = p >> 10;               // p / N_
    const int c = threadIdx.x;           // channel

    const float inv_level = 1.0f / 8.0f;
    const float xa  = ma[p * 2 + 0] * inv_level;
    const float ya  = ma[p * 2 + 1] * inv_level;
    const float ubx = mb[p * 2 + 0] * inv_level;
    const float uby = mb[p * 2 + 1] * inv_level;
    const float nx  = noise[p * 2 + 0];
    const float ny  = noise[p * 2 + 1];
    const float xs  = 2.0f * nx - 1.0f + ubx;
    const float ys  = 2.0f * ny - 1.0f + uby;

    // ---------- f_t: bilinear from F_a ----------
    const float ax0f = floorf(xa), ay0f = floorf(ya);
    const float awx = xa - ax0f, awy = ya - ay0f;
    int ax0 = min(max((int)ax0f, 0), W_ - 1);
    int ax1 = min(ax0 + 1, W_ - 1);
    int ay0 = min(max((int)ay0f, 0), H_ - 1);
    int ay1 = min(ay0 + 1, H_ - 1);
    const float* __restrict__ fa = Fa + ((size_t)b * C_ + c) * HW_;
    const float av00 = fa[ay0 * W_ + ax0];
    const float av01 = fa[ay0 * W_ + ax1];
    const float av10 = fa[ay1 * W_ + ax0];
    const float av11 = fa[ay1 * W_ + ax1];
    const float ft = av00 * (1.f - awx) * (1.f - awy)
                   + av01 * awx * (1.f - awy)
                   + av10 * (1.f - awx) * awy
                   + av11 * awx * awy;

    // ---------- f_s, Jx, Jy: from F_b (value + on-the-fly central differences) ----------
    const float bx0f = floorf(xs), by0f = floorf(ys);
    const float wx = xs - bx0f, wy = ys - by0f;
    int x0 = min(max((int)bx0f, 0), W_ - 1);
    int x1 = min(x0 + 1, W_ - 1);
    int y0 = min(max((int)by0f, 0), H_ - 1);
    int y1 = min(y0 + 1, H_ - 1);
    int xm = max(x0 - 1, 0);
    int xp = min(x1 + 1, W_ - 1);
    int ym = max(y0 - 1, 0);
    int yp = min(y1 + 1, H_ - 1);
    const float* __restrict__ fb = Fb + ((size_t)b * C_ + c) * HW_;

    // rows y0,y1 at cols xm,x0,x1,xp ; rows ym,yp at cols x0,x1  (12 loads)
    const float r0m = fb[y0 * W_ + xm], r00 = fb[y0 * W_ + x0];
    const float r01 = fb[y0 * W_ + x1], r0p = fb[y0 * W_ + xp];
    const float r1m = fb[y1 * W_ + xm], r10 = fb[y1 * W_ + x0];
    const float r11 = fb[y1 * W_ + x1], r1p = fb[y1 * W_ + xp];
    const float rm0 = fb[ym * W_ + x0], rm1 = fb[ym * W_ + x1];
    const float rp0 = fb[yp * W_ + x0], rp1 = fb[yp * W_ + x1];

    const float w00 = (1.f - wx) * (1.f - wy);
    const float w01 = wx * (1.f - wy);
    const float w10 = (1.f - wx) * wy;
    const float w11 = wx * wy;

    const float fs = r00 * w00 + r01 * w01 + r10 * w10 + r11 * w11;
    // gx at the 4 corners: 0.5*(right - left)
    const float jx = 0.5f * ((r01 - r0m) * w00 + (r0p - r00) * w01
                           + (r11 - r1m) * w10 + (r1p - r10) * w11);
    // gy at the 4 corners: 0.5*(down - up)
    const float jy = 0.5f * ((r10 - rm0) * w00 + (r11 - rm1) * w01
                           + (rp0 - r00) * w10 + (rp1 - r01) * w11);

    // ---------- 9 channel reductions ----------
    float vals[9];
    vals[0] = ft * ft;
    vals[1] = fs * fs;
    vals[2] = jx * fs;
    vals[3] = jx * ft;
    vals[4] = jy * fs;
    vals[5] = jy * ft;
    vals[6] = jx * jx;
    vals[7] = jx * jy;
    vals[8] = jy * jy;

    #pragma unroll
    for (int k = 0; k < 9; ++k)
        vals[k] = wave_reduce(vals[k]);

    __shared__ float sm[2][9];
    const int wid = threadIdx.x >> 6;
    const int lane = threadIdx.x & 63;
    if (lane == 0) {
        #pragma unroll
        for (int k = 0; k < 9; ++k) sm[wid][k] = vals[k];
    }
    __syncthreads();

    if (threadIdx.x == 0) {
        float s[9];
        #pragma unroll
        for (int k = 0; k < 9; ++k) s[k] = sm[0][k] + sm[1][k];

        const float nt = fmaxf(sqrtf(s[0]), 1e-12f);
        const float ns = fmaxf(sqrtf(s[1]), 1e-12f);
        const float b0 = s[2] / ns - s[3] / nt;
        const float b1 = s[4] / ns - s[5] / nt;
        const float H00 = s[6] + 1e-9f;
        const float H01 = s[7];
        const float H11 = s[8] + 1e-9f;
        const float det = H00 * H11 - H01 * H01;
        const float inv = 1.0f / det;
        const float u0 = (H11 * b0 - H01 * b1) * inv;   // (Hinv @ b)[0]
        const float u1 = (H00 * b1 - H01 * b0) * inv;   // (Hinv @ b)[1]
        const float d0 = (ubx - xs) + u0;               // diff = ub - miu
        const float d1 = (uby - ys) + u1;
        const float quad = d0 * (H00 * d0 + H01 * d1) + d1 * (H01 * d0 + H11 * d1);
        ws_e1[p] = 0.5f * quad;
        ws_ld[p] = logf(det);
    }
}

// Single-block deterministic reduction of the 4096 per-point partials.
__global__ __launch_bounds__(256) void gn_reduce_kernel(
    const float* __restrict__ ws_e1, const float* __restrict__ ws_ld,
    float* __restrict__ out)
{
    __shared__ double sm1[256];
    __shared__ double sm2[256];
    double a1 = 0.0, a2 = 0.0;
    for (int i = threadIdx.x; i < NPTS; i += 256) {
        a1 += (double)ws_e1[i];
        a2 += (double)ws_ld[i];
    }
    sm1[threadIdx.x] = a1;
    sm2[threadIdx.x] = a2;
    __syncthreads();
    for (int s = 128; s > 0; s >>= 1) {
        if (threadIdx.x < s) {
            sm1[threadIdx.x] += sm1[threadIdx.x + s];
            sm2[threadIdx.x] += sm2[threadIdx.x + s];
        }
        __syncthreads();
    }
    if (threadIdx.x == 0) {
        const double e1 = sm1[0];
        const double sum_ld = sm2[0];
        // reference: log(2*pi) computed in fp32
        const double log2pi = (double)logf(6.283185307179586f);
        const double e2 = (double)NPTS * log2pi - 0.5 * sum_ld;
        const double e = 1.0 * e1 + (2.0 / 7.0) * e2;   // E1_LAMDA=1, E2_LAMDA=2/7
        out[0] = (float)(0.3 * e);                      // GN_LAMDA * e
        out[1] = (float)e1;
        out[2] = (float)e2;
    }
}

extern "C" void kernel_launch(void* const* d_in, const int* in_sizes, int n_in,
                              void* d_out, int out_size, void* d_ws, size_t ws_size,
                              hipStream_t stream) {
    const float* Fa    = (const float*)d_in[0];
    const float* Fb    = (const float*)d_in[1];
    const float* ma    = (const float*)d_in[2];
    const float* mb    = (const float*)d_in[3];
    const float* noise = (const float*)d_in[4];
    float* out = (float*)d_out;

    float* ws_e1 = (float*)d_ws;          // 4096 floats
    float* ws_ld = ws_e1 + NPTS;          // 4096 floats (total 32 KiB)

    gn_point_kernel<<<NPTS, 128, 0, stream>>>(Fa, Fb, ma, mb, noise, ws_e1, ws_ld);
    gn_reduce_kernel<<<1, 256, 0, stream>>>(ws_e1, ws_ld, out);
}